// Round 6
// baseline (132.899 us; speedup 1.0000x reference)
//
#include <hip/hip_runtime.h>

typedef __bf16 bf16;
typedef __bf16 bf16x8 __attribute__((ext_vector_type(8)));
typedef float f32x4 __attribute__((ext_vector_type(4)));
typedef unsigned short u16;
typedef u16 u16x8 __attribute__((ext_vector_type(8)));
typedef unsigned int u32;

#define BATCH 64
#define NODES 512
#define AMINO 64
#define NTYPES 20
#define RMAX 13
#define NJT 26           // 26 j-tiles of 16

__constant__ int c_res_lens[NTYPES] = {4,10,7,7,5,8,8,3,9,7,7,8,7,10,6,5,6,13,11,6};

// fp32 -> bf16, exact round-to-nearest-even, pure bit ops
__device__ __forceinline__ u16 f2bf(float f) {
    u32 u; __builtin_memcpy(&u, &f, 4);
    u32 r = u + 0x7FFFu + ((u >> 16) & 1u);
    return (u16)(r >> 16);
}

// int64 vs int32 probe for type_ids: odd words all-zero <=> int64 high halves.
__device__ __forceinline__ int detect_i64(const int* __restrict__ p) {
    int z = 0;
#pragma unroll
    for (int k = 0; k < 16; ++k) z |= p[2 * k + 1];
    return z == 0;
}
__device__ __forceinline__ int tid_at(const int* __restrict__ p, int n, int is64) {
    return p[is64 ? 2 * n : n];
}

// ---------------- prep kernel ----------------
// blocks 0..259: swizzle fp32 W into B-fragment-linear bf16 layout:
//   chunk = (t*NJT + jt)*2 + kh ; lane l holds W[t][a=kh*32+(l>>4)*8+i][j=jt*16+(l&15)]
// block 260: exclusive prefix sum of residue lengths -> meta[n] = t | len<<5 | s0<<9
__global__ __launch_bounds__(256) void prep_kernel(const float* __restrict__ W,
                                                   const int* __restrict__ type_ids,
                                                   u16* __restrict__ wswz,
                                                   int* __restrict__ meta) {
    if (blockIdx.x < 260) {
        int g = blockIdx.x * 256 + threadIdx.x;     // over 20*26*2*64 = 66560 lanes
        if (g >= NTYPES * NJT * 2 * 64) return;
        int lane = g & 63;
        int chunk = g >> 6;
        int kh = chunk & 1;
        int tj = chunk >> 1;
        int t = tj / NJT;
        int jt = tj - t * NJT;
        int q = lane >> 4, c = lane & 15;
        int a0 = kh * 32 + q * 8;
        int j = jt * 16 + c;
        u16x8 v;
#pragma unroll
        for (int i = 0; i < 8; ++i)
            v[i] = f2bf(W[(size_t)(t * AMINO + a0 + i) * (RMAX * 32) + j]);
        *(u16x8*)(wswz + (size_t)chunk * 512 + lane * 8) = v;
    } else {
        __shared__ int s[256];
        int is64 = detect_i64(type_ids);
        int i = threadIdx.x;
        int t0 = tid_at(type_ids, 2 * i, is64);
        int t1 = tid_at(type_ids, 2 * i + 1, is64);
        int la = c_res_lens[t0];
        int lb = c_res_lens[t1];
        s[i] = la + lb;
        __syncthreads();
        for (int off = 1; off < 256; off <<= 1) {
            int v = (i >= off) ? s[i - off] : 0;
            __syncthreads();
            s[i] += v;
            __syncthreads();
        }
        int excl = s[i] - (la + lb);     // exclusive over pairs
        meta[2 * i]     = t0 | (la << 5) | (excl << 9);
        meta[2 * i + 1] = t1 | (lb << 5) | ((excl + la) << 9);
    }
}

// ---------------- main kernel ----------------
// block = (node n, m-tile m of 16 batches). No LDS, no barrier.
// 4 waves; wave w handles residues r = w, w+4, ...
__global__ __launch_bounds__(256) void main_kernel(const float* __restrict__ x,
                                                   const int* __restrict__ meta,
                                                   const u16* __restrict__ wswz,
                                                   float* __restrict__ out,
                                                   int G) {
    const int bid = blockIdx.x;
    const int n = bid >> 2;
    const int m = bid & 3;
    const int tid = threadIdx.x;
    const int w = tid >> 6;
    const int l = tid & 63;
    const int q = l >> 4;
    const int c = l & 15;

    const int mt = meta[n];
    const int t = mt & 31;
    const int len = (mt >> 5) & 15;
    const int s0 = mt >> 9;

    // ---- build A fragments straight from global x ----
    // lane (q,c): A row = batch b16 = c; k = kh*32 + q*8 + i.
    // x[(m*16+c), n, a, v] is contiguous in (a,v): 24 floats = 96 B per (kh,q).
    union Frag { u16x8 u; bf16x8 b; };
    Frag Af[3][2];
    {
        const float* base = x + ((size_t)(m * 16 + c) * NODES + n) * 192;
#pragma unroll
        for (int kh = 0; kh < 2; ++kh) {
            f32x4 xv[6];
            const float* src = base + (kh * 32 + q * 8) * 3;
#pragma unroll
            for (int i6 = 0; i6 < 6; ++i6)
                xv[i6] = *(const f32x4*)(src + i6 * 4);
            const float* f = (const float*)xv;
#pragma unroll
            for (int v = 0; v < 3; ++v)
#pragma unroll
                for (int i = 0; i < 8; ++i)
                    Af[v][kh].u[i] = f2bf(f[i * 3 + v]);
        }
    }

    for (int r = w; r < len; r += 4) {
        Frag Bf[2][2];
#pragma unroll
        for (int jj = 0; jj < 2; ++jj)
#pragma unroll
            for (int kh = 0; kh < 2; ++kh)
                Bf[jj][kh].u = *(const u16x8*)(wswz +
                                (size_t)((t * NJT + (2 * r + jj)) * 2 + kh) * 512 + l * 8);

        const int g = s0 + r;   // output row index within G

        f32x4 acc[2][3];
        const f32x4 z = {0.f, 0.f, 0.f, 0.f};
#pragma unroll
        for (int jj = 0; jj < 2; ++jj)
#pragma unroll
            for (int v = 0; v < 3; ++v) {
                f32x4 a0 = __builtin_amdgcn_mfma_f32_16x16x32_bf16(Af[v][0].b, Bf[jj][0].b, z, 0, 0, 0);
                acc[jj][v] = __builtin_amdgcn_mfma_f32_16x16x32_bf16(Af[v][1].b, Bf[jj][1].b, a0, 0, 0, 0);
            }

        // stores: lane writes 12 contiguous B per (reg,jj); 16 c-lanes cover
        // 192 B contiguous; full 384-B rows written across jj.
#pragma unroll
        for (int reg = 0; reg < 4; ++reg) {
            float* rowp = out + ((size_t)(m * 16 + q * 4 + reg) * G + g) * 96;
#pragma unroll
            for (int jj = 0; jj < 2; ++jj) {
                float tmp[3] = {acc[jj][0][reg], acc[jj][1][reg], acc[jj][2][reg]};
                __builtin_memcpy(rowp + (jj * 16 + c) * 3, tmp, 12);
            }
        }
    }
}

extern "C" void kernel_launch(void* const* d_in, const int* in_sizes, int n_in,
                              void* d_out, int out_size, void* d_ws, size_t ws_size,
                              hipStream_t stream) {
    const float* x = (const float*)d_in[0];    // fp32 (B, N, 64, 3)
    const float* W = (const float*)d_in[1];    // fp32 (20, 64, 416)
    const int* type_ids = (const int*)d_in[2]; // int32 or int64 (autodetected), 512
    int G = out_size / (BATCH * 32 * 3);       // valid (node,residue) rows

    int* meta = (int*)d_ws;                                // 512 ints
    u16* wswz = (u16*)((char*)d_ws + 4096);                // 20*26*2*512 bf16 ≈ 1.06 MB

    prep_kernel<<<261, 256, 0, stream>>>(W, type_ids, wswz, meta);
    main_kernel<<<NODES * 4, 256, 0, stream>>>(x, meta, wswz, (float*)d_out, G);
}